// Round 4
// baseline (624.140 us; speedup 1.0000x reference)
//
#include <hip/hip_runtime.h>

// GNN: 3x (GraphConv -> BatchNorm -> ReLU) -> global_mean_pool -> Linear, fp32.
//
//  - CSR build once (hist -> parallel 3-stage scan -> reorder), reused 3x.
//  - Per layer: aggregate (gather-side, atomic-free, lazy BN+ReLU) ->
//    fused GEMM (concat-K 256, lazy BN on X path, col-stats in epilogue,
//    double-buffered LDS, k-major A tile, 8x4 micro-tile) -> finalize.
//  - Pool applies layer-3 (scale, shift), segmented over sorted batch.

constexpr int   NN   = 50000;
constexpr int   NE   = 800000;
constexpr int   DH   = 128;
constexpr int   NC   = 10;
constexpr int   NG   = 1024;
constexpr float EPSV = 1e-5f;
constexpr int   NB   = (NN + 255) / 256;   // 196 scan blocks

// ------------------------------------------------------------- CSR build ---
__global__ __launch_bounds__(256) void hist_kernel(
    const int* __restrict__ dst, int* __restrict__ deg)
{
    int e = blockIdx.x * 256 + threadIdx.x;
    if (e < NE) atomicAdd(&deg[dst[e]], 1);
}

__global__ __launch_bounds__(256) void psum_kernel(
    const int* __restrict__ deg, int* __restrict__ bsum)
{
    int t = threadIdx.x;
    int i = blockIdx.x * 256 + t;
    int d = (i < NN) ? deg[i] : 0;
#pragma unroll
    for (int off = 32; off > 0; off >>= 1) d += __shfl_down(d, off, 64);
    __shared__ int w4[4];
    if ((t & 63) == 0) w4[t >> 6] = d;
    __syncthreads();
    if (t == 0) bsum[blockIdx.x] = w4[0] + w4[1] + w4[2] + w4[3];
}

__global__ __launch_bounds__(256) void scan_bsums_kernel(
    const int* __restrict__ bsum, int* __restrict__ bbase)
{
    __shared__ int tmp[256];
    int t = threadIdx.x;
    int v = (t < NB) ? bsum[t] : 0;
    tmp[t] = v;
    __syncthreads();
    for (int off = 1; off < 256; off <<= 1) {
        int u = (t >= off) ? tmp[t - off] : 0;
        __syncthreads();
        tmp[t] += u;
        __syncthreads();
    }
    if (t < NB) bbase[t] = tmp[t] - v;   // exclusive
}

__global__ __launch_bounds__(256) void offsets_kernel(
    const int* __restrict__ deg, const int* __restrict__ bbase,
    int* __restrict__ offsets, int* __restrict__ cursor)
{
    __shared__ int tmp[256];
    int t = threadIdx.x;
    int i = blockIdx.x * 256 + t;
    int d = (i < NN) ? deg[i] : 0;
    tmp[t] = d;
    __syncthreads();
    for (int off = 1; off < 256; off <<= 1) {
        int u = (t >= off) ? tmp[t - off] : 0;
        __syncthreads();
        tmp[t] += u;
        __syncthreads();
    }
    int incl = tmp[t];
    int base = bbase[blockIdx.x];
    if (i < NN) {
        int o = base + incl - d;
        offsets[i] = o;
        cursor[i]  = o;
        if (i == NN - 1) offsets[NN] = base + incl;
    }
}

__global__ __launch_bounds__(256) void reorder_kernel(
    const int* __restrict__ src, const int* __restrict__ dst,
    int* __restrict__ cursor, int* __restrict__ csr_src)
{
    int e = blockIdx.x * 256 + threadIdx.x;
    if (e < NE) {
        int pos = atomicAdd(&cursor[dst[e]], 1);
        csr_src[pos] = src[e];
    }
}

// -------------------------------------------------------------- aggregate ---
template <bool TRANSFORM>
__global__ __launch_bounds__(256) void aggregate_kernel(
    const float* __restrict__ x, const int* __restrict__ offsets,
    const int* __restrict__ csr_src, const float* __restrict__ sc,
    const float* __restrict__ sh, float* __restrict__ agg)
{
    int tid = blockIdx.x * 256 + threadIdx.x;
    int node = tid >> 5;
    if (node >= NN) return;
    int c4 = (tid & 31) << 2;

    float4 sc4, sh4;
    if (TRANSFORM) {
        sc4 = *reinterpret_cast<const float4*>(sc + c4);
        sh4 = *reinterpret_cast<const float4*>(sh + c4);
    }
    auto xf = [&](float4 v) -> float4 {
        if (TRANSFORM) {
            v.x = fmaxf(fmaf(v.x, sc4.x, sh4.x), 0.f);
            v.y = fmaxf(fmaf(v.y, sc4.y, sh4.y), 0.f);
            v.z = fmaxf(fmaf(v.z, sc4.z, sh4.z), 0.f);
            v.w = fmaxf(fmaf(v.w, sc4.w, sh4.w), 0.f);
        }
        return v;
    };

    int beg = offsets[node], end = offsets[node + 1];
    float4 acc = make_float4(0.f, 0.f, 0.f, 0.f);
    int e = beg;
    for (; e + 3 < end; e += 4) {
        int s0 = csr_src[e], s1 = csr_src[e + 1];
        int s2 = csr_src[e + 2], s3 = csr_src[e + 3];
        float4 v0 = xf(*reinterpret_cast<const float4*>(x + (size_t)s0 * DH + c4));
        float4 v1 = xf(*reinterpret_cast<const float4*>(x + (size_t)s1 * DH + c4));
        float4 v2 = xf(*reinterpret_cast<const float4*>(x + (size_t)s2 * DH + c4));
        float4 v3 = xf(*reinterpret_cast<const float4*>(x + (size_t)s3 * DH + c4));
        acc.x += (v0.x + v1.x) + (v2.x + v3.x);
        acc.y += (v0.y + v1.y) + (v2.y + v3.y);
        acc.z += (v0.z + v1.z) + (v2.z + v3.z);
        acc.w += (v0.w + v1.w) + (v2.w + v3.w);
    }
    for (; e < end; ++e) {
        int s0 = csr_src[e];
        float4 v0 = xf(*reinterpret_cast<const float4*>(x + (size_t)s0 * DH + c4));
        acc.x += v0.x; acc.y += v0.y; acc.z += v0.z; acc.w += v0.w;
    }
    *reinterpret_cast<float4*>(agg + (size_t)node * DH + c4) = acc;
}

// ------------------------------------------------------------------- gemm ---
// OUT = t(X) @ Wr + A @ Wl + bias, t = lazy BN+ReLU (TRANSFORM) or identity.
// 64x128 tile, 256 threads, 8 rows x 4 cols per thread, K-step 32,
// double-buffered LDS, k-major A tile. Col stats accumulated in epilogue.
template <bool TRANSFORM>
__global__ __launch_bounds__(256) void gemm_fused_kernel(
    const float* __restrict__ X, const float* __restrict__ A,
    const float* __restrict__ Wr, const float* __restrict__ Wl,
    const float* __restrict__ bias, const float* __restrict__ scIn,
    const float* __restrict__ shIn, float* __restrict__ OUT,
    float* __restrict__ stats)
{
    __shared__ float sAT[2][32][68];    // k-major: [buf][k][row], pad 68
    __shared__ float sW[2][32][128];
    __shared__ float sScale[DH], sShift[DH];

    const int tid  = threadIdx.x;
    const int col0 = (tid & 31) * 4;      // 32 distinct float4 cols -> 2-way
    const int ty8  = (tid >> 5) * 8;      // 8 rows per thread, broadcast reads
    const int row0 = blockIdx.x * 64;
    const int rA   = tid >> 2;            // staging row 0..63
    const int cA   = (tid & 3) * 4;       // staging k base
    const int wRow = tid >> 5;            // W staging k row base
    const int wCol = (tid & 31) * 4;

    if (TRANSFORM && tid < DH) {
        sScale[tid] = scIn[tid];
        sShift[tid] = shIn[tid];
    }
    __syncthreads();

    float4 pA0, pA1, pW0, pW1, pW2, pW3;

    auto loadTile = [&](int t) {
        const float* inp = (t < 4) ? X : A;
        const float* Wp  = (t < 4) ? Wr : Wl;
        const int kb = (t * 32) & 127;
        int grow = row0 + rA;
        pA0 = make_float4(0.f, 0.f, 0.f, 0.f);
        pA1 = pA0;
        if (grow < NN) {
            const float* p = inp + (size_t)grow * DH + kb + cA;
            pA0 = *reinterpret_cast<const float4*>(p);
            pA1 = *reinterpret_cast<const float4*>(p + 16);
            if (TRANSFORM && t < 4) {
                int cb = kb + cA;
                pA0.x = fmaxf(fmaf(pA0.x, sScale[cb + 0],  sShift[cb + 0]),  0.f);
                pA0.y = fmaxf(fmaf(pA0.y, sScale[cb + 1],  sShift[cb + 1]),  0.f);
                pA0.z = fmaxf(fmaf(pA0.z, sScale[cb + 2],  sShift[cb + 2]),  0.f);
                pA0.w = fmaxf(fmaf(pA0.w, sScale[cb + 3],  sShift[cb + 3]),  0.f);
                pA1.x = fmaxf(fmaf(pA1.x, sScale[cb + 16], sShift[cb + 16]), 0.f);
                pA1.y = fmaxf(fmaf(pA1.y, sScale[cb + 17], sShift[cb + 17]), 0.f);
                pA1.z = fmaxf(fmaf(pA1.z, sScale[cb + 18], sShift[cb + 18]), 0.f);
                pA1.w = fmaxf(fmaf(pA1.w, sScale[cb + 19], sShift[cb + 19]), 0.f);
            }
        }
        const float* wb = Wp + (size_t)(kb + wRow) * DH + wCol;
        pW0 = *reinterpret_cast<const float4*>(wb);
        pW1 = *reinterpret_cast<const float4*>(wb + 8 * DH);
        pW2 = *reinterpret_cast<const float4*>(wb + 16 * DH);
        pW3 = *reinterpret_cast<const float4*>(wb + 24 * DH);
    };

    auto writeTile = [&](int b) {
        sAT[b][cA + 0][rA]  = pA0.x; sAT[b][cA + 1][rA]  = pA0.y;
        sAT[b][cA + 2][rA]  = pA0.z; sAT[b][cA + 3][rA]  = pA0.w;
        sAT[b][cA + 16][rA] = pA1.x; sAT[b][cA + 17][rA] = pA1.y;
        sAT[b][cA + 18][rA] = pA1.z; sAT[b][cA + 19][rA] = pA1.w;
        *reinterpret_cast<float4*>(&sW[b][wRow][wCol])      = pW0;
        *reinterpret_cast<float4*>(&sW[b][wRow + 8][wCol])  = pW1;
        *reinterpret_cast<float4*>(&sW[b][wRow + 16][wCol]) = pW2;
        *reinterpret_cast<float4*>(&sW[b][wRow + 24][wCol]) = pW3;
    };

    float acc[8][4];
#pragma unroll
    for (int r = 0; r < 8; ++r)
#pragma unroll
        for (int j = 0; j < 4; ++j) acc[r][j] = 0.f;

    loadTile(0);
    writeTile(0);
    __syncthreads();

    for (int t = 0; t < 8; ++t) {
        const int cur = t & 1;
        if (t < 7) loadTile(t + 1);

#pragma unroll
        for (int kk = 0; kk < 32; ++kk) {
            float4 A0 = *reinterpret_cast<const float4*>(&sAT[cur][kk][ty8]);
            float4 A1 = *reinterpret_cast<const float4*>(&sAT[cur][kk][ty8 + 4]);
            float4 w  = *reinterpret_cast<const float4*>(&sW[cur][kk][col0]);
            float av[8] = {A0.x, A0.y, A0.z, A0.w, A1.x, A1.y, A1.z, A1.w};
            float wv[4] = {w.x, w.y, w.z, w.w};
#pragma unroll
            for (int r = 0; r < 8; ++r)
#pragma unroll
                for (int j = 0; j < 4; ++j)
                    acc[r][j] = fmaf(av[r], wv[j], acc[r][j]);
        }

        if (t < 7) writeTile(cur ^ 1);
        __syncthreads();
    }

    // epilogue: bias, store, column stats
    float bv[4];
#pragma unroll
    for (int j = 0; j < 4; ++j) bv[j] = bias[col0 + j];

    float s_[4] = {0.f, 0.f, 0.f, 0.f}, q_[4] = {0.f, 0.f, 0.f, 0.f};

#pragma unroll
    for (int r = 0; r < 8; ++r) {
        int grow = row0 + ty8 + r;
        if (grow < NN) {
            float o[4];
#pragma unroll
            for (int j = 0; j < 4; ++j) {
                o[j] = acc[r][j] + bv[j];
                s_[j] += o[j];
                q_[j] += o[j] * o[j];
            }
            *reinterpret_cast<float4*>(OUT + (size_t)grow * DH + col0) =
                make_float4(o[0], o[1], o[2], o[3]);
        }
    }

    // reduce: lanes l and l+32 share columns
#pragma unroll
    for (int j = 0; j < 4; ++j) {
        s_[j] += __shfl_xor(s_[j], 32, 64);
        q_[j] += __shfl_xor(q_[j], 32, 64);
    }
    // reuse dead sAT buffer for the cross-wave reduction (post-sync safe)
    float* ldsS = &sAT[0][0][0];         // [4][128]
    float* ldsQ = ldsS + 512;            // [4][128]
    int lane = tid & 63, wave = tid >> 6;
    if (lane < 32) {
#pragma unroll
        for (int j = 0; j < 4; ++j) {
            ldsS[wave * DH + lane * 4 + j] = s_[j];
            ldsQ[wave * DH + lane * 4 + j] = q_[j];
        }
    }
    __syncthreads();
    if (tid < DH) {
        float s = ldsS[tid] + ldsS[DH + tid] + ldsS[2 * DH + tid] + ldsS[3 * DH + tid];
        float q = ldsQ[tid] + ldsQ[DH + tid] + ldsQ[2 * DH + tid] + ldsQ[3 * DH + tid];
        atomicAdd(&stats[tid], s);
        atomicAdd(&stats[DH + tid], q);
    }
}

// --------------------------------------------------------------- finalize ---
__global__ __launch_bounds__(128) void finalize_kernel(
    const float* __restrict__ stats, const float* __restrict__ gamma,
    const float* __restrict__ beta, float* __restrict__ sc,
    float* __restrict__ sh)
{
    int j = threadIdx.x;
    float mean = stats[j] * (1.f / NN);
    float var  = stats[DH + j] * (1.f / NN) - mean * mean;
    float s = rsqrtf(var + EPSV) * gamma[j];
    sc[j] = s;
    sh[j] = beta[j] - mean * s;
}

// ------------------------------------------------------------------- pool ---
__global__ __launch_bounds__(256) void ghist_kernel(
    const int* __restrict__ batch, int* __restrict__ gdeg)
{
    int n = blockIdx.x * 256 + threadIdx.x;
    if (n < NN) atomicAdd(&gdeg[batch[n]], 1);
}

__global__ __launch_bounds__(1024) void gscan_kernel(
    const int* __restrict__ gdeg, int* __restrict__ goff)
{
    __shared__ int part[1024];
    int t = threadIdx.x;
    part[t] = gdeg[t];
    __syncthreads();
    for (int off = 1; off < 1024; off <<= 1) {
        int v = (t >= off) ? part[t - off] : 0;
        __syncthreads();
        part[t] += v;
        __syncthreads();
    }
    goff[t + 1] = part[t];
    if (t == 0) goff[0] = 0;
}

__global__ __launch_bounds__(128) void pool_seg_kernel(
    const float* __restrict__ H, const int* __restrict__ goff,
    const float* __restrict__ sc, const float* __restrict__ sh,
    float* __restrict__ pooled)
{
    int g = blockIdx.x;
    int j = threadIdx.x;
    int beg = goff[g], end = goff[g + 1];
    float s = 0.f;
    for (int n = beg; n < end; ++n) s += H[(size_t)n * DH + j];
    float cnt = (float)(end - beg);
    float v = s * sc[j] + cnt * sh[j];
    pooled[(size_t)g * DH + j] = v / fmaxf(cnt, 1.f);
}

__global__ __launch_bounds__(64) void classify_kernel(
    const float* __restrict__ pooled, const float* __restrict__ wcls,
    const float* __restrict__ bcls, float* __restrict__ out)
{
    int g = blockIdx.x;
    int lane = threadIdx.x;
    float p0 = pooled[(size_t)g * DH + lane];
    float p1 = pooled[(size_t)g * DH + 64 + lane];
#pragma unroll
    for (int c = 0; c < NC; ++c) {
        float v = p0 * wcls[lane * NC + c] + p1 * wcls[(64 + lane) * NC + c];
#pragma unroll
        for (int off = 32; off > 0; off >>= 1) v += __shfl_down(v, off, 64);
        if (lane == 0) out[(size_t)g * NC + c] = v + bcls[c];
    }
}

// ----------------------------------------------------------------- launch ---
extern "C" void kernel_launch(void* const* d_in, const int* in_sizes, int n_in,
                              void* d_out, int out_size, void* d_ws, size_t ws_size,
                              hipStream_t stream)
{
    const float* x    = (const float*)d_in[0];
    const int*   ei   = (const int*)d_in[1];
    const int*   batch= (const int*)d_in[2];
    const float* wr1  = (const float*)d_in[3];
    const float* wl1  = (const float*)d_in[4];
    const float* b1   = (const float*)d_in[5];
    const float* wr2  = (const float*)d_in[6];
    const float* wl2  = (const float*)d_in[7];
    const float* b2   = (const float*)d_in[8];
    const float* wr3  = (const float*)d_in[9];
    const float* wl3  = (const float*)d_in[10];
    const float* b3   = (const float*)d_in[11];
    const float* g1   = (const float*)d_in[12];
    const float* be1  = (const float*)d_in[13];
    const float* g2   = (const float*)d_in[14];
    const float* be2  = (const float*)d_in[15];
    const float* g3   = (const float*)d_in[16];
    const float* be3  = (const float*)d_in[17];
    const float* wcls = (const float*)d_in[18];
    const float* bcls = (const float*)d_in[19];
    float* out = (float*)d_out;

    const int* srcp = ei;
    const int* dstp = ei + NE;

    char* ws = (char*)d_ws;
    const size_t featB = (size_t)NN * DH * sizeof(float);
    size_t off = 0;
    auto alloc = [&](size_t bytes) {
        void* p = ws + off;
        off += (bytes + 255) & ~(size_t)255;
        return p;
    };
    float* agg     = (float*)alloc(featB);
    float* hA      = (float*)alloc(featB);
    float* hB      = (float*)alloc(featB);
    float* stats   = (float*)alloc(1024);
    float* pooled  = (float*)alloc((size_t)NG * DH * sizeof(float));
    int*   deg     = (int*)alloc(NN * sizeof(int));
    int*   offsets = (int*)alloc((NN + 1) * sizeof(int));
    int*   cursor  = (int*)alloc(NN * sizeof(int));
    int*   csr_src = (int*)alloc(NE * sizeof(int));
    int*   gdeg    = (int*)alloc(NG * sizeof(int));
    int*   goff    = (int*)alloc((NG + 1) * sizeof(int));
    int*   bsum    = (int*)alloc(NB * sizeof(int));
    int*   bbase   = (int*)alloc(NB * sizeof(int));
    float* sc1 = (float*)alloc(DH * 4); float* sh1 = (float*)alloc(DH * 4);
    float* sc2 = (float*)alloc(DH * 4); float* sh2 = (float*)alloc(DH * 4);
    float* sc3 = (float*)alloc(DH * 4); float* sh3 = (float*)alloc(DH * 4);

    const int edgeBlocks = (NE + 255) / 256;
    const int nodeBlocks = (NN + 255) / 256;     // == NB
    const int aggBlocks  = (NN * 32 + 255) / 256;
    const int gemmBlocks = (NN + 63) / 64;

    // ---- CSR build (once)
    hipMemsetAsync(deg, 0, NN * sizeof(int), stream);
    hist_kernel<<<edgeBlocks, 256, 0, stream>>>(dstp, deg);
    psum_kernel<<<NB, 256, 0, stream>>>(deg, bsum);
    scan_bsums_kernel<<<1, 256, 0, stream>>>(bsum, bbase);
    offsets_kernel<<<NB, 256, 0, stream>>>(deg, bbase, offsets, cursor);
    reorder_kernel<<<edgeBlocks, 256, 0, stream>>>(srcp, dstp, cursor, csr_src);

    // ---- graph ranges for pooling
    hipMemsetAsync(gdeg, 0, NG * sizeof(int), stream);
    ghist_kernel<<<nodeBlocks, 256, 0, stream>>>(batch, gdeg);
    gscan_kernel<<<1, 1024, 0, stream>>>(gdeg, goff);

    // ---- layer 1
    aggregate_kernel<false><<<aggBlocks, 256, 0, stream>>>(x, offsets, csr_src, nullptr, nullptr, agg);
    hipMemsetAsync(stats, 0, 1024, stream);
    gemm_fused_kernel<false><<<gemmBlocks, 256, 0, stream>>>(x, agg, wr1, wl1, b1, nullptr, nullptr, hA, stats);
    finalize_kernel<<<1, 128, 0, stream>>>(stats, g1, be1, sc1, sh1);

    // ---- layer 2
    aggregate_kernel<true><<<aggBlocks, 256, 0, stream>>>(hA, offsets, csr_src, sc1, sh1, agg);
    hipMemsetAsync(stats, 0, 1024, stream);
    gemm_fused_kernel<true><<<gemmBlocks, 256, 0, stream>>>(hA, agg, wr2, wl2, b2, sc1, sh1, hB, stats);
    finalize_kernel<<<1, 128, 0, stream>>>(stats, g2, be2, sc2, sh2);

    // ---- layer 3
    aggregate_kernel<true><<<aggBlocks, 256, 0, stream>>>(hB, offsets, csr_src, sc2, sh2, agg);
    hipMemsetAsync(stats, 0, 1024, stream);
    gemm_fused_kernel<true><<<gemmBlocks, 256, 0, stream>>>(hB, agg, wr3, wl3, b3, sc2, sh2, hA, stats);
    finalize_kernel<<<1, 128, 0, stream>>>(stats, g3, be3, sc3, sh3);

    // ---- pool (applies BN3, no ReLU) + classify
    pool_seg_kernel<<<NG, 128, 0, stream>>>(hA, goff, sc3, sh3, pooled);
    classify_kernel<<<NG, 64, 0, stream>>>(pooled, wcls, bcls, out);
}

// Round 5
// 488.536 us; speedup vs baseline: 1.2776x; 1.2776x over previous
//
#include <hip/hip_runtime.h>

// GNN: 3x (GraphConv -> BatchNorm -> ReLU) -> global_mean_pool -> Linear, fp32.
//
//  - CSR build once (hist -> parallel 3-stage scan -> reorder), reused 3x.
//  - Per layer: aggregate (gather-side, atomic-free, lazy BN+ReLU) ->
//    fused GEMM (concat-K 256, lazy BN on X path, col-stats in epilogue,
//    single-buffered LDS [round-3 dbuf blew VGPRs 56->232], k-major A tile,
//    8x4 micro-tile for conflict-free ds_read) -> finalize.
//  - Pool applies layer-3 (scale, shift), segmented over sorted batch.

constexpr int   NN   = 50000;
constexpr int   NE   = 800000;
constexpr int   DH   = 128;
constexpr int   NC   = 10;
constexpr int   NG   = 1024;
constexpr float EPSV = 1e-5f;
constexpr int   NB   = (NN + 255) / 256;   // 196 scan blocks

// ------------------------------------------------------------- CSR build ---
__global__ __launch_bounds__(256) void hist_kernel(
    const int* __restrict__ dst, int* __restrict__ deg)
{
    int e = blockIdx.x * 256 + threadIdx.x;
    if (e < NE) atomicAdd(&deg[dst[e]], 1);
}

__global__ __launch_bounds__(256) void psum_kernel(
    const int* __restrict__ deg, int* __restrict__ bsum)
{
    int t = threadIdx.x;
    int i = blockIdx.x * 256 + t;
    int d = (i < NN) ? deg[i] : 0;
#pragma unroll
    for (int off = 32; off > 0; off >>= 1) d += __shfl_down(d, off, 64);
    __shared__ int w4[4];
    if ((t & 63) == 0) w4[t >> 6] = d;
    __syncthreads();
    if (t == 0) bsum[blockIdx.x] = w4[0] + w4[1] + w4[2] + w4[3];
}

__global__ __launch_bounds__(256) void scan_bsums_kernel(
    const int* __restrict__ bsum, int* __restrict__ bbase)
{
    __shared__ int tmp[256];
    int t = threadIdx.x;
    int v = (t < NB) ? bsum[t] : 0;
    tmp[t] = v;
    __syncthreads();
    for (int off = 1; off < 256; off <<= 1) {
        int u = (t >= off) ? tmp[t - off] : 0;
        __syncthreads();
        tmp[t] += u;
        __syncthreads();
    }
    if (t < NB) bbase[t] = tmp[t] - v;   // exclusive
}

__global__ __launch_bounds__(256) void offsets_kernel(
    const int* __restrict__ deg, const int* __restrict__ bbase,
    int* __restrict__ offsets, int* __restrict__ cursor)
{
    __shared__ int tmp[256];
    int t = threadIdx.x;
    int i = blockIdx.x * 256 + t;
    int d = (i < NN) ? deg[i] : 0;
    tmp[t] = d;
    __syncthreads();
    for (int off = 1; off < 256; off <<= 1) {
        int u = (t >= off) ? tmp[t - off] : 0;
        __syncthreads();
        tmp[t] += u;
        __syncthreads();
    }
    int incl = tmp[t];
    int base = bbase[blockIdx.x];
    if (i < NN) {
        int o = base + incl - d;
        offsets[i] = o;
        cursor[i]  = o;
        if (i == NN - 1) offsets[NN] = base + incl;
    }
}

__global__ __launch_bounds__(256) void reorder_kernel(
    const int* __restrict__ src, const int* __restrict__ dst,
    int* __restrict__ cursor, int* __restrict__ csr_src)
{
    int e = blockIdx.x * 256 + threadIdx.x;
    if (e < NE) {
        int pos = atomicAdd(&cursor[dst[e]], 1);
        csr_src[pos] = src[e];
    }
}

// -------------------------------------------------------------- aggregate ---
template <bool TRANSFORM>
__global__ __launch_bounds__(256) void aggregate_kernel(
    const float* __restrict__ x, const int* __restrict__ offsets,
    const int* __restrict__ csr_src, const float* __restrict__ sc,
    const float* __restrict__ sh, float* __restrict__ agg)
{
    int tid = blockIdx.x * 256 + threadIdx.x;
    int node = tid >> 5;
    if (node >= NN) return;
    int c4 = (tid & 31) << 2;

    float4 sc4, sh4;
    if (TRANSFORM) {
        sc4 = *reinterpret_cast<const float4*>(sc + c4);
        sh4 = *reinterpret_cast<const float4*>(sh + c4);
    }
    auto xf = [&](float4 v) -> float4 {
        if (TRANSFORM) {
            v.x = fmaxf(fmaf(v.x, sc4.x, sh4.x), 0.f);
            v.y = fmaxf(fmaf(v.y, sc4.y, sh4.y), 0.f);
            v.z = fmaxf(fmaf(v.z, sc4.z, sh4.z), 0.f);
            v.w = fmaxf(fmaf(v.w, sc4.w, sh4.w), 0.f);
        }
        return v;
    };

    int beg = offsets[node], end = offsets[node + 1];
    float4 acc = make_float4(0.f, 0.f, 0.f, 0.f);
    int e = beg;
    for (; e + 3 < end; e += 4) {
        int s0 = csr_src[e], s1 = csr_src[e + 1];
        int s2 = csr_src[e + 2], s3 = csr_src[e + 3];
        float4 v0 = xf(*reinterpret_cast<const float4*>(x + (size_t)s0 * DH + c4));
        float4 v1 = xf(*reinterpret_cast<const float4*>(x + (size_t)s1 * DH + c4));
        float4 v2 = xf(*reinterpret_cast<const float4*>(x + (size_t)s2 * DH + c4));
        float4 v3 = xf(*reinterpret_cast<const float4*>(x + (size_t)s3 * DH + c4));
        acc.x += (v0.x + v1.x) + (v2.x + v3.x);
        acc.y += (v0.y + v1.y) + (v2.y + v3.y);
        acc.z += (v0.z + v1.z) + (v2.z + v3.z);
        acc.w += (v0.w + v1.w) + (v2.w + v3.w);
    }
    for (; e < end; ++e) {
        int s0 = csr_src[e];
        float4 v0 = xf(*reinterpret_cast<const float4*>(x + (size_t)s0 * DH + c4));
        acc.x += v0.x; acc.y += v0.y; acc.z += v0.z; acc.w += v0.w;
    }
    *reinterpret_cast<float4*>(agg + (size_t)node * DH + c4) = acc;
}

// ------------------------------------------------------------------- gemm ---
// OUT = t(X) @ Wr + A @ Wl + bias, t = lazy BN+ReLU (TRANSFORM) or identity.
// 64x128 tile, 256 threads, 8 rows x 4 cols per thread, K-step 32,
// single-buffered LDS (keeps VGPR low), k-major A tile (conflict-free reads).
template <bool TRANSFORM>
__global__ __launch_bounds__(256) void gemm_fused_kernel(
    const float* __restrict__ X, const float* __restrict__ A,
    const float* __restrict__ Wr, const float* __restrict__ Wl,
    const float* __restrict__ bias, const float* __restrict__ scIn,
    const float* __restrict__ shIn, float* __restrict__ OUT,
    float* __restrict__ stats)
{
    __shared__ float sAT[32][68];       // k-major: [k][row], pad 68
    __shared__ float sW[32][128];
    __shared__ float sScale[DH], sShift[DH];

    const int tid  = threadIdx.x;
    const int col0 = (tid & 31) * 4;      // 32 distinct float4 cols -> 2-way (free)
    const int ty8  = (tid >> 5) * 8;      // 8 rows per thread, broadcast reads
    const int row0 = blockIdx.x * 64;
    const int rA   = tid >> 2;            // staging row 0..63
    const int cA   = (tid & 3) * 4;       // staging k base
    const int wRow = tid >> 5;            // W staging k row base
    const int wCol = (tid & 31) * 4;

    if (TRANSFORM && tid < DH) {
        sScale[tid] = scIn[tid];
        sShift[tid] = shIn[tid];
    }
    __syncthreads();

    float acc[8][4];
#pragma unroll
    for (int r = 0; r < 8; ++r)
#pragma unroll
        for (int j = 0; j < 4; ++j) acc[r][j] = 0.f;

    const int grow = row0 + rA;
    for (int t = 0; t < 8; ++t) {
        const float* inp = (t < 4) ? X : A;
        const float* Wp  = (t < 4) ? Wr : Wl;
        const int kb = (t * 32) & 127;

        // stage A tile (k-major) ------------------------------------------
        float4 v0 = make_float4(0.f, 0.f, 0.f, 0.f), v1 = v0;
        if (grow < NN) {
            const float* p = inp + (size_t)grow * DH + kb + cA;
            v0 = *reinterpret_cast<const float4*>(p);
            v1 = *reinterpret_cast<const float4*>(p + 16);
            if (TRANSFORM && t < 4) {
                int cb = kb + cA;
                v0.x = fmaxf(fmaf(v0.x, sScale[cb + 0],  sShift[cb + 0]),  0.f);
                v0.y = fmaxf(fmaf(v0.y, sScale[cb + 1],  sShift[cb + 1]),  0.f);
                v0.z = fmaxf(fmaf(v0.z, sScale[cb + 2],  sShift[cb + 2]),  0.f);
                v0.w = fmaxf(fmaf(v0.w, sScale[cb + 3],  sShift[cb + 3]),  0.f);
                v1.x = fmaxf(fmaf(v1.x, sScale[cb + 16], sShift[cb + 16]), 0.f);
                v1.y = fmaxf(fmaf(v1.y, sScale[cb + 17], sShift[cb + 17]), 0.f);
                v1.z = fmaxf(fmaf(v1.z, sScale[cb + 18], sShift[cb + 18]), 0.f);
                v1.w = fmaxf(fmaf(v1.w, sScale[cb + 19], sShift[cb + 19]), 0.f);
            }
        }
        const float* wb = Wp + (size_t)(kb + wRow) * DH + wCol;
        float4 w0 = *reinterpret_cast<const float4*>(wb);
        float4 w1 = *reinterpret_cast<const float4*>(wb + 8 * DH);
        float4 w2 = *reinterpret_cast<const float4*>(wb + 16 * DH);
        float4 w3 = *reinterpret_cast<const float4*>(wb + 24 * DH);

        sAT[cA + 0][rA]  = v0.x; sAT[cA + 1][rA]  = v0.y;
        sAT[cA + 2][rA]  = v0.z; sAT[cA + 3][rA]  = v0.w;
        sAT[cA + 16][rA] = v1.x; sAT[cA + 17][rA] = v1.y;
        sAT[cA + 18][rA] = v1.z; sAT[cA + 19][rA] = v1.w;
        *reinterpret_cast<float4*>(&sW[wRow][wCol])      = w0;
        *reinterpret_cast<float4*>(&sW[wRow + 8][wCol])  = w1;
        *reinterpret_cast<float4*>(&sW[wRow + 16][wCol]) = w2;
        *reinterpret_cast<float4*>(&sW[wRow + 24][wCol]) = w3;
        __syncthreads();

        // compute ----------------------------------------------------------
#pragma unroll
        for (int kk = 0; kk < 32; ++kk) {
            float4 A0 = *reinterpret_cast<const float4*>(&sAT[kk][ty8]);
            float4 A1 = *reinterpret_cast<const float4*>(&sAT[kk][ty8 + 4]);
            float4 w  = *reinterpret_cast<const float4*>(&sW[kk][col0]);
            float av[8] = {A0.x, A0.y, A0.z, A0.w, A1.x, A1.y, A1.z, A1.w};
            float wv[4] = {w.x, w.y, w.z, w.w};
#pragma unroll
            for (int r = 0; r < 8; ++r)
#pragma unroll
                for (int j = 0; j < 4; ++j)
                    acc[r][j] = fmaf(av[r], wv[j], acc[r][j]);
        }
        __syncthreads();
    }

    // epilogue: bias, store, column stats
    float bv[4];
#pragma unroll
    for (int j = 0; j < 4; ++j) bv[j] = bias[col0 + j];

    float s_[4] = {0.f, 0.f, 0.f, 0.f}, q_[4] = {0.f, 0.f, 0.f, 0.f};

#pragma unroll
    for (int r = 0; r < 8; ++r) {
        int orow = row0 + ty8 + r;
        if (orow < NN) {
            float o[4];
#pragma unroll
            for (int j = 0; j < 4; ++j) {
                o[j] = acc[r][j] + bv[j];
                s_[j] += o[j];
                q_[j] += o[j] * o[j];
            }
            *reinterpret_cast<float4*>(OUT + (size_t)orow * DH + col0) =
                make_float4(o[0], o[1], o[2], o[3]);
        }
    }

    // reduce: lanes l and l+32 share columns
#pragma unroll
    for (int j = 0; j < 4; ++j) {
        s_[j] += __shfl_xor(s_[j], 32, 64);
        q_[j] += __shfl_xor(q_[j], 32, 64);
    }
    // reuse dead sAT buffer for the cross-wave reduction
    float* ldsS = &sAT[0][0];            // [4][128]
    float* ldsQ = ldsS + 512;            // [4][128]
    int lane = tid & 63, wave = tid >> 6;
    if (lane < 32) {
#pragma unroll
        for (int j = 0; j < 4; ++j) {
            ldsS[wave * DH + lane * 4 + j] = s_[j];
            ldsQ[wave * DH + lane * 4 + j] = q_[j];
        }
    }
    __syncthreads();
    if (tid < DH) {
        float s = ldsS[tid] + ldsS[DH + tid] + ldsS[2 * DH + tid] + ldsS[3 * DH + tid];
        float q = ldsQ[tid] + ldsQ[DH + tid] + ldsQ[2 * DH + tid] + ldsQ[3 * DH + tid];
        atomicAdd(&stats[tid], s);
        atomicAdd(&stats[DH + tid], q);
    }
}

// --------------------------------------------------------------- finalize ---
__global__ __launch_bounds__(128) void finalize_kernel(
    const float* __restrict__ stats, const float* __restrict__ gamma,
    const float* __restrict__ beta, float* __restrict__ sc,
    float* __restrict__ sh)
{
    int j = threadIdx.x;
    float mean = stats[j] * (1.f / NN);
    float var  = stats[DH + j] * (1.f / NN) - mean * mean;
    float s = rsqrtf(var + EPSV) * gamma[j];
    sc[j] = s;
    sh[j] = beta[j] - mean * s;
}

// ------------------------------------------------------------------- pool ---
__global__ __launch_bounds__(256) void ghist_kernel(
    const int* __restrict__ batch, int* __restrict__ gdeg)
{
    int n = blockIdx.x * 256 + threadIdx.x;
    if (n < NN) atomicAdd(&gdeg[batch[n]], 1);
}

__global__ __launch_bounds__(1024) void gscan_kernel(
    const int* __restrict__ gdeg, int* __restrict__ goff)
{
    __shared__ int part[1024];
    int t = threadIdx.x;
    part[t] = gdeg[t];
    __syncthreads();
    for (int off = 1; off < 1024; off <<= 1) {
        int v = (t >= off) ? part[t - off] : 0;
        __syncthreads();
        part[t] += v;
        __syncthreads();
    }
    goff[t + 1] = part[t];
    if (t == 0) goff[0] = 0;
}

__global__ __launch_bounds__(128) void pool_seg_kernel(
    const float* __restrict__ H, const int* __restrict__ goff,
    const float* __restrict__ sc, const float* __restrict__ sh,
    float* __restrict__ pooled)
{
    int g = blockIdx.x;
    int j = threadIdx.x;
    int beg = goff[g], end = goff[g + 1];
    float s = 0.f;
    for (int n = beg; n < end; ++n) s += H[(size_t)n * DH + j];
    float cnt = (float)(end - beg);
    float v = s * sc[j] + cnt * sh[j];
    pooled[(size_t)g * DH + j] = v / fmaxf(cnt, 1.f);
}

__global__ __launch_bounds__(64) void classify_kernel(
    const float* __restrict__ pooled, const float* __restrict__ wcls,
    const float* __restrict__ bcls, float* __restrict__ out)
{
    int g = blockIdx.x;
    int lane = threadIdx.x;
    float p0 = pooled[(size_t)g * DH + lane];
    float p1 = pooled[(size_t)g * DH + 64 + lane];
#pragma unroll
    for (int c = 0; c < NC; ++c) {
        float v = p0 * wcls[lane * NC + c] + p1 * wcls[(64 + lane) * NC + c];
#pragma unroll
        for (int off = 32; off > 0; off >>= 1) v += __shfl_down(v, off, 64);
        if (lane == 0) out[(size_t)g * NC + c] = v + bcls[c];
    }
}

// ----------------------------------------------------------------- launch ---
extern "C" void kernel_launch(void* const* d_in, const int* in_sizes, int n_in,
                              void* d_out, int out_size, void* d_ws, size_t ws_size,
                              hipStream_t stream)
{
    const float* x    = (const float*)d_in[0];
    const int*   ei   = (const int*)d_in[1];
    const int*   batch= (const int*)d_in[2];
    const float* wr1  = (const float*)d_in[3];
    const float* wl1  = (const float*)d_in[4];
    const float* b1   = (const float*)d_in[5];
    const float* wr2  = (const float*)d_in[6];
    const float* wl2  = (const float*)d_in[7];
    const float* b2   = (const float*)d_in[8];
    const float* wr3  = (const float*)d_in[9];
    const float* wl3  = (const float*)d_in[10];
    const float* b3   = (const float*)d_in[11];
    const float* g1   = (const float*)d_in[12];
    const float* be1  = (const float*)d_in[13];
    const float* g2   = (const float*)d_in[14];
    const float* be2  = (const float*)d_in[15];
    const float* g3   = (const float*)d_in[16];
    const float* be3  = (const float*)d_in[17];
    const float* wcls = (const float*)d_in[18];
    const float* bcls = (const float*)d_in[19];
    float* out = (float*)d_out;

    const int* srcp = ei;
    const int* dstp = ei + NE;

    char* ws = (char*)d_ws;
    const size_t featB = (size_t)NN * DH * sizeof(float);
    size_t off = 0;
    auto alloc = [&](size_t bytes) {
        void* p = ws + off;
        off += (bytes + 255) & ~(size_t)255;
        return p;
    };
    float* agg     = (float*)alloc(featB);
    float* hA      = (float*)alloc(featB);
    float* hB      = (float*)alloc(featB);
    float* stats   = (float*)alloc(1024);
    float* pooled  = (float*)alloc((size_t)NG * DH * sizeof(float));
    int*   deg     = (int*)alloc(NN * sizeof(int));
    int*   offsets = (int*)alloc((NN + 1) * sizeof(int));
    int*   cursor  = (int*)alloc(NN * sizeof(int));
    int*   csr_src = (int*)alloc(NE * sizeof(int));
    int*   gdeg    = (int*)alloc(NG * sizeof(int));
    int*   goff    = (int*)alloc((NG + 1) * sizeof(int));
    int*   bsum    = (int*)alloc(NB * sizeof(int));
    int*   bbase   = (int*)alloc(NB * sizeof(int));
    float* sc1 = (float*)alloc(DH * 4); float* sh1 = (float*)alloc(DH * 4);
    float* sc2 = (float*)alloc(DH * 4); float* sh2 = (float*)alloc(DH * 4);
    float* sc3 = (float*)alloc(DH * 4); float* sh3 = (float*)alloc(DH * 4);

    const int edgeBlocks = (NE + 255) / 256;
    const int nodeBlocks = (NN + 255) / 256;     // == NB
    const int aggBlocks  = (NN * 32 + 255) / 256;
    const int gemmBlocks = (NN + 63) / 64;

    // ---- CSR build (once)
    hipMemsetAsync(deg, 0, NN * sizeof(int), stream);
    hist_kernel<<<edgeBlocks, 256, 0, stream>>>(dstp, deg);
    psum_kernel<<<NB, 256, 0, stream>>>(deg, bsum);
    scan_bsums_kernel<<<1, 256, 0, stream>>>(bsum, bbase);
    offsets_kernel<<<NB, 256, 0, stream>>>(deg, bbase, offsets, cursor);
    reorder_kernel<<<edgeBlocks, 256, 0, stream>>>(srcp, dstp, cursor, csr_src);

    // ---- graph ranges for pooling
    hipMemsetAsync(gdeg, 0, NG * sizeof(int), stream);
    ghist_kernel<<<nodeBlocks, 256, 0, stream>>>(batch, gdeg);
    gscan_kernel<<<1, 1024, 0, stream>>>(gdeg, goff);

    // ---- layer 1
    aggregate_kernel<false><<<aggBlocks, 256, 0, stream>>>(x, offsets, csr_src, nullptr, nullptr, agg);
    hipMemsetAsync(stats, 0, 1024, stream);
    gemm_fused_kernel<false><<<gemmBlocks, 256, 0, stream>>>(x, agg, wr1, wl1, b1, nullptr, nullptr, hA, stats);
    finalize_kernel<<<1, 128, 0, stream>>>(stats, g1, be1, sc1, sh1);

    // ---- layer 2
    aggregate_kernel<true><<<aggBlocks, 256, 0, stream>>>(hA, offsets, csr_src, sc1, sh1, agg);
    hipMemsetAsync(stats, 0, 1024, stream);
    gemm_fused_kernel<true><<<gemmBlocks, 256, 0, stream>>>(hA, agg, wr2, wl2, b2, sc1, sh1, hB, stats);
    finalize_kernel<<<1, 128, 0, stream>>>(stats, g2, be2, sc2, sh2);

    // ---- layer 3
    aggregate_kernel<true><<<aggBlocks, 256, 0, stream>>>(hB, offsets, csr_src, sc2, sh2, agg);
    hipMemsetAsync(stats, 0, 1024, stream);
    gemm_fused_kernel<true><<<gemmBlocks, 256, 0, stream>>>(hB, agg, wr3, wl3, b3, sc2, sh2, hA, stats);
    finalize_kernel<<<1, 128, 0, stream>>>(stats, g3, be3, sc3, sh3);

    // ---- pool (applies BN3, no ReLU) + classify
    pool_seg_kernel<<<NG, 128, 0, stream>>>(hA, goff, sc3, sh3, pooled);
    classify_kernel<<<NG, 64, 0, stream>>>(pooled, wcls, bcls, out);
}